// Round 1
// baseline (472.849 us; speedup 1.0000x reference)
//
#include <hip/hip_runtime.h>
#include <math.h>

#define WAVE 64
constexpr int   CC      = 100;    // classes (fixed by problem)
constexpr int   MAXM    = 160;    // max thresholds per class (~0.05*P+1 ≈ 132)
constexpr int   SORTCAP = 4096;   // LDS sort capacity (P ~ 2621 ± 51)
constexpr float LSMOOTH = 0.1f;

// ---------------- K1: per-row softmax stats (wave per row) ----------------
__global__ __launch_bounds__(256) void k1_rowstats(
    const float* __restrict__ pred, const int* __restrict__ targets,
    const float* __restrict__ weight, float* __restrict__ L_out,
    float* __restrict__ pos_out, float* __restrict__ ce_partial, int N)
{
    const int lane = threadIdx.x & (WAVE - 1);
    const int wid  = threadIdx.x >> 6;
    const int wavesPerBlock = blockDim.x >> 6;
    const int gwave = blockIdx.x * wavesPerBlock + wid;
    const int totalWaves = gridDim.x * wavesPerBlock;

    const bool has2 = (lane < CC - WAVE);          // lanes 0..35 hold a 2nd class
    const float w0 = weight[lane];
    const float w1 = has2 ? weight[lane + WAVE] : 0.0f;
    float Wl = w0 + w1;                            // total weight sum
    #pragma unroll
    for (int off = 32; off; off >>= 1) Wl += __shfl_xor(Wl, off, WAVE);

    float ce_acc = 0.0f;
    for (int row = gwave; row < N; row += totalWaves) {
        const float* rp = pred + (size_t)row * CC;
        float v0 = rp[lane];
        float v1 = has2 ? rp[lane + WAVE] : -INFINITY;
        float vmax = fmaxf(v0, v1);
        #pragma unroll
        for (int off = 32; off; off >>= 1) vmax = fmaxf(vmax, __shfl_xor(vmax, off, WAVE));
        float z  = __expf(v0 - vmax) + (has2 ? __expf(v1 - vmax) : 0.0f);
        float ws = w0 * v0 + (has2 ? w1 * v1 : 0.0f);
        #pragma unroll
        for (int off = 32; off; off >>= 1) {
            z  += __shfl_xor(z,  off, WAVE);
            ws += __shfl_xor(ws, off, WAVE);
        }
        float L = vmax + __logf(z);                // log-sum-exp of the row
        int t = targets[row];
        float pt = rp[t];                          // wave-uniform cached load
        if (lane == 0) { L_out[row] = L; pos_out[row] = pt - L; }
        // ce_n = -( (1-LS)*w_t*lp_t + (LS/C)*sum_c w_c*lp_c ),  lp = pred - L
        ce_acc += -((1.0f - LSMOOTH) * weight[t] * (pt - L)
                    + (LSMOOTH / CC) * (ws - Wl * L));
    }
    __shared__ float cered[8];
    if (lane == 0) cered[wid] = ce_acc;
    __syncthreads();
    if (threadIdx.x == 0) {
        float s = 0.0f;
        for (int i = 0; i < wavesPerBlock; ++i) s += cered[i];
        ce_partial[blockIdx.x] = s;
    }
}

// --------- K2: per class, gather positive scores, sort, emit m smallest ---------
__global__ __launch_bounds__(1024) void k2_classsort(
    const int* __restrict__ targets, const float* __restrict__ pos_score,
    float* __restrict__ u, int* __restrict__ m_arr, int* __restrict__ P_arr,
    float* __restrict__ wm_arr, int N)
{
    __shared__ float s[SORTCAP];
    __shared__ int cnt;
    const int c = blockIdx.x;
    if (threadIdx.x == 0) cnt = 0;
    __syncthreads();
    for (int n = threadIdx.x; n < N; n += blockDim.x) {
        if (targets[n] == c) {
            int i = atomicAdd(&cnt, 1);
            if (i < SORTCAP) s[i] = pos_score[n];
        }
    }
    __syncthreads();
    const int P = min(cnt, SORTCAP);
    for (int i = P + threadIdx.x; i < SORTCAP; i += blockDim.x) s[i] = INFINITY;
    __syncthreads();
    // bitonic sort ascending over SORTCAP
    for (int k = 2; k <= SORTCAP; k <<= 1) {
        for (int j = k >> 1; j > 0; j >>= 1) {
            for (int i = threadIdx.x; i < SORTCAP; i += blockDim.x) {
                int ixj = i ^ j;
                if (ixj > i) {
                    float a = s[i], b = s[ixj];
                    bool up = ((i & k) == 0);
                    if ((a > b) == up) { s[i] = b; s[ixj] = a; }
                }
            }
            __syncthreads();
        }
    }
    double Kd = 0.95 * (double)P;
    int kf = (int)floor(Kd);
    int m = P - kf;
    if (m > MAXM) m = MAXM;
    if (m < 0) m = 0;
    if (threadIdx.x == 0) {
        m_arr[c] = m; P_arr[c] = P;
        wm_arr[c] = (float)((double)(kf + 1) - Kd);   // weight of the last (fractional) step
    }
    for (int i = threadIdx.x; i < m; i += blockDim.x)
        u[c * MAXM + i] = s[i];                       // m smallest positive scores, ascending
}

// --------- K3: stream all scores, count below-threshold contributions ---------
__global__ __launch_bounds__(256) void k3_accum(
    const float4* __restrict__ pred4, const float* __restrict__ L,
    const float* __restrict__ u, const int* __restrict__ m_arr,
    int* __restrict__ g_cnt, int* __restrict__ g_sum, int total4)
{
    __shared__ float umax[CC];
    __shared__ int sm_m[CC];
    __shared__ int ls_cnt[CC], ls_sum[CC];
    for (int c = threadIdx.x; c < CC; c += blockDim.x) {
        int m = m_arr[c];
        sm_m[c] = m;
        umax[c] = (m > 0) ? u[c * MAXM + m - 1] : -INFINITY;
        ls_cnt[c] = 0; ls_sum[c] = 0;
    }
    __syncthreads();
    const int stride = gridDim.x * blockDim.x;
    for (int i = blockIdx.x * blockDim.x + threadIdx.x; i < total4; i += stride) {
        float4 v = pred4[i];
        int n  = i / (CC / 4);                 // 100 % 4 == 0: float4 never crosses a row
        int c0 = (i - n * (CC / 4)) * 4;
        float Ln = L[n];
        float sc[4] = { v.x - Ln, v.y - Ln, v.z - Ln, v.w - Ln };
        #pragma unroll
        for (int q = 0; q < 4; ++q) {
            int c = c0 + q;
            if (sc[q] < umax[c]) {             // ~5% take this path
                int m = sm_m[c];
                const float* uc = u + c * MAXM;
                int l = 0, r = m;              // upper_bound: # thresholds <= sc
                while (l < r) {
                    int mid = (l + r) >> 1;
                    if (uc[mid] <= sc[q]) l = mid + 1; else r = mid;
                }
                atomicAdd(&ls_cnt[c], 1);
                atomicAdd(&ls_sum[c], m - 1 - l);
            }
        }
    }
    __syncthreads();
    for (int c = threadIdx.x; c < CC; c += blockDim.x) {
        if (ls_cnt[c] > 0) {
            atomicAdd(&g_cnt[c], ls_cnt[c]);
            atomicAdd(&g_sum[c], ls_sum[c]);
        }
    }
}

// ---------------- K4: finalize (CE reduce + per-class pAUC + combine) ----------------
__global__ __launch_bounds__(256) void k4_final(
    const float* __restrict__ ce_partial, int nPartial,
    const float* __restrict__ weight, const int* __restrict__ P_arr,
    const int* __restrict__ m_arr, const float* __restrict__ wm_arr,
    const int* __restrict__ g_cnt, const int* __restrict__ g_sum,
    float* __restrict__ out, int N)
{
    __shared__ double r1[256], r2[256], r3[256];
    double ce = 0.0;
    for (int i = threadIdx.x; i < nPartial; i += blockDim.x) ce += (double)ce_partial[i];
    double p = 0.0, wsum = 0.0;
    for (int c = threadIdx.x; c < CC; c += blockDim.x) {
        int P = P_arr[c], m = m_arr[c];
        double wgt = (double)weight[c];
        long long Nn = (long long)N - P;
        if (P > 0 && Nn > 0 && m > 0) {
            double wm = (double)wm_arr[c];
            double S   = (double)g_sum[c] + wm * (double)g_cnt[c];
            double sub = 0.5 * (double)(m - 1) * (double)(m - 2) + wm * (double)(m - 1);
            double pc  = (S - sub) / ((double)Nn * (double)P);
            if (pc < 0.0) pc = 0.0;
            p += pc * wgt;
        }
        wsum += wgt;
    }
    r1[threadIdx.x] = ce; r2[threadIdx.x] = p; r3[threadIdx.x] = wsum;
    __syncthreads();
    for (int off = blockDim.x >> 1; off; off >>= 1) {
        if ((int)threadIdx.x < off) {
            r1[threadIdx.x] += r1[threadIdx.x + off];
            r2[threadIdx.x] += r2[threadIdx.x + off];
            r3[threadIdx.x] += r3[threadIdx.x + off];
        }
        __syncthreads();
    }
    if (threadIdx.x == 0) {
        double ce_loss = r1[0] / (double)N;
        double avg = r2[0] / (r3[0] * 0.05);           // MAX_PAUC = R1-R0 = 0.05
        avg = fmin(fmax(avg, 0.0), 1.0);
        out[0] = (float)(0.5 * ce_loss + 0.5 * (1.0 - avg * avg));
    }
}

extern "C" void kernel_launch(void* const* d_in, const int* in_sizes, int n_in,
                              void* d_out, int out_size, void* d_ws, size_t ws_size,
                              hipStream_t stream) {
    (void)n_in; (void)out_size; (void)ws_size;
    const float* pred    = (const float*)d_in[0];
    const int*   targets = (const int*)d_in[1];
    const float* weight  = (const float*)d_in[2];
    float* out = (float*)d_out;
    const int N = in_sizes[1];

    constexpr int K1_BLOCKS = 4096;
    char* base = (char*)d_ws;
    float* L_ws       = (float*)(base);                               // N floats
    float* pos_ws     = (float*)(base + (size_t)N * 4);               // N floats
    float* ce_partial = (float*)(base + (size_t)N * 8);               // K1_BLOCKS floats
    char* p = base + (size_t)N * 8 + (size_t)K1_BLOCKS * 4;
    float* u      = (float*)p; p += (size_t)CC * MAXM * 4;
    int*   m_arr  = (int*)p;   p += CC * 4;
    int*   P_arr  = (int*)p;   p += CC * 4;
    float* wm_arr = (float*)p; p += CC * 4;
    int*   g_cnt  = (int*)p;   p += CC * 4;
    int*   g_sum  = (int*)p;   /* contiguous with g_cnt */

    hipMemsetAsync(g_cnt, 0, (size_t)CC * 4 * 2, stream);             // zero g_cnt+g_sum

    k1_rowstats<<<K1_BLOCKS, 256, 0, stream>>>(pred, targets, weight, L_ws, pos_ws,
                                               ce_partial, N);
    k2_classsort<<<CC, 1024, 0, stream>>>(targets, pos_ws, u, m_arr, P_arr, wm_arr, N);
    const int total4 = (int)((size_t)N * CC / 4);
    k3_accum<<<2048, 256, 0, stream>>>((const float4*)pred, L_ws, u, m_arr,
                                       g_cnt, g_sum, total4);
    k4_final<<<1, 256, 0, stream>>>(ce_partial, K1_BLOCKS, weight, P_arr, m_arr, wm_arr,
                                    g_cnt, g_sum, out, N);
}